// Round 8
// baseline (170.129 us; speedup 1.0000x reference)
//
#include <hip/hip_runtime.h>
#include <math.h>

#ifndef M_PI
#define M_PI 3.14159265358979323846
#endif

#define ROWS 128
#define NN   4096
#define MAGIC 0x13572468u

// ws byte offsets
#define TW_OFF   0        // float2[8192]  tw[k] = exp(-2*pi*i*k/8192)
#define CA_OFF   65536    // float2[8192]  cA[m] = chirp[4096+m]
#define GEIN_OFF 131072   // float2[8192]  Ec_even/8192 (time domain, natural)
#define GOIN_OFF 196608   // float2[8192]  Ec_odd /8192 (time domain, natural)
#define GE_OFF   262144   // float2[8192]  DIF8192(gein)  (scrambled order)
#define GO_OFF   327680   // float2[8192]  DIF8192(goin)  (scrambled order)
#define SC_OFF   393216   // float2        Aphi/128
#define FLAG_OFF 393224   // uint[2]       Ghat-ready flags (poisoned 0xAA.. each launch)
#define GT_OFF   458752   // float2[4096]  twist table g[drev6(p)]/4096 (scrambled)

// LDS bank-conflict swizzle (bijective within [0,8192) and [0,4096))
__device__ __forceinline__ int swz(int i) { return i ^ ((i >> 5) & 31); }

// base-4 digit reversal of a 12-bit value (6 digits)
__device__ __forceinline__ int drev6(int v) {
    unsigned r = __brev((unsigned)v) >> 20;
    return (int)(((r & 0x555u) << 1) | ((r & 0xAAAu) >> 1));
}

__device__ __forceinline__ float2 cmul(float2 a, float2 b) {
    return make_float2(a.x * b.x - a.y * b.y, a.x * b.y + a.y * b.x);
}

// ---- radix-2 stage, span 8192 (full-length FFT only; g_fft path) ----
template<int INV>
__device__ __forceinline__ void r2_8192(float* re, float* im,
                                        const float2* __restrict__ tw, int tid) {
    __syncthreads();
#pragma unroll
    for (int it = 0; it < 4; ++it) {
        const int n = tid + it * 1024;
        const int i0 = swz(n), i1 = swz(n + 4096);
        const float ur = re[i0], ui = im[i0];
        const float vr = re[i1], vi = im[i1];
        const float2 w = tw[n];
        const float wi = INV ? -w.y : w.y;
        if (!INV) {
            const float dr = ur - vr, di = ui - vi;
            re[i0] = ur + vr;            im[i0] = ui + vi;
            re[i1] = dr * w.x - di * wi; im[i1] = dr * wi + di * w.x;
        } else {
            const float br = vr * w.x - vi * wi, bi = vr * wi + vi * w.x;
            re[i0] = ur + br; im[i0] = ui + bi;
            re[i1] = ur - br; im[i1] = ui - bi;
        }
    }
}

// ---- radix-4 stage, span 2^LS. NITER=1: 4096-pt array, NITER=2: 8192-pt ----
// tw is 8192-based; twiddle shift 13-LS is valid for BOTH sizes (4096 exponent
// doubles, table index doubles).
template<int INV, int LS, int NITER>
__device__ __forceinline__ void r4_stage(float* re, float* im,
                                         const float2* __restrict__ tw, int tid) {
    __syncthreads();
    const int Q = 1 << (LS - 2);
    const int TS = 13 - LS;
#pragma unroll
    for (int it = 0; it < NITER; ++it) {
        const int gi = tid + it * 1024;
        const int q  = gi & (Q - 1);
        const int base = ((gi >> (LS - 2)) << LS) | q;
        const int i0 = swz(base), i1 = swz(base + Q), i2 = swz(base + 2 * Q), i3 = swz(base + 3 * Q);
        float ar = re[i0], ai = im[i0];
        float br = re[i1], bi = im[i1];
        float cr = re[i2], ci = im[i2];
        float dr = re[i3], di = im[i3];
        const float2 w1 = tw[q << TS];
        const float2 w2 = tw[(2 * q) << TS];
        const float2 w3 = tw[(3 * q) << TS];
        const float w1i = INV ? -w1.y : w1.y;
        const float w2i = INV ? -w2.y : w2.y;
        const float w3i = INV ? -w3.y : w3.y;
        if (!INV) {
            const float t0r = ar + cr, t0i = ai + ci;
            const float t1r = ar - cr, t1i = ai - ci;
            const float t2r = br + dr, t2i = bi + di;
            const float t3r = br - dr, t3i = bi - di;
            re[i0] = t0r + t2r; im[i0] = t0i + t2i;
            const float y1r = t1r + t3i, y1i = t1i - t3r;
            re[i1] = y1r * w1.x - y1i * w1i; im[i1] = y1r * w1i + y1i * w1.x;
            const float y2r = t0r - t2r, y2i = t0i - t2i;
            re[i2] = y2r * w2.x - y2i * w2i; im[i2] = y2r * w2i + y2i * w2.x;
            const float y3r = t1r - t3i, y3i = t1i + t3r;
            re[i3] = y3r * w3.x - y3i * w3i; im[i3] = y3r * w3i + y3i * w3.x;
        } else {
            const float b1r = br * w1.x - bi * w1i, b1i = br * w1i + bi * w1.x;
            const float b2r = cr * w2.x - ci * w2i, b2i = cr * w2i + ci * w2.x;
            const float b3r = dr * w3.x - di * w3i, b3i = dr * w3i + di * w3.x;
            const float s0r = ar + b2r, s0i = ai + b2i;
            const float s1r = ar - b2r, s1i = ai - b2i;
            const float s2r = b1r + b3r, s2i = b1i + b3i;
            const float s3r = b1r - b3r, s3i = b1i - b3i;
            re[i0] = s0r + s2r; im[i0] = s0i + s2i;
            re[i1] = s1r - s3i; im[i1] = s1i + s3r;
            re[i2] = s0r - s2r; im[i2] = s0i - s2i;
            re[i3] = s1r + s3i; im[i3] = s1i - s3r;
        }
    }
}

__global__ __launch_bounds__(256) void build_tables_k(const float* __restrict__ order,
                                                      char* __restrict__ ws) {
    const int gid  = blockIdx.x * 256 + threadIdx.x;
    const int nthr = gridDim.x * 256;
    const double a    = (double)order[0];
    const double phi  = a * (M_PI * 0.5);
    const double sp   = sin(phi);
    const double alph = -M_PI * tan(phi * 0.5);
    const double beta = M_PI / sp;
    float2* tw   = (float2*)(ws + TW_OFF);
    float2* cA   = (float2*)(ws + CA_OFF);
    float2* gein = (float2*)(ws + GEIN_OFF);
    float2* goin = (float2*)(ws + GOIN_OFF);
    float2* sc   = (float2*)(ws + SC_OFF);
    float2* Gt   = (float2*)(ws + GT_OFF);
    for (int k = gid; k < 8192; k += nthr) {
        double th = -2.0 * M_PI * (double)k / 8192.0;
        tw[k] = make_float2((float)cos(th), (float)sin(th));
    }
    for (int m = gid; m < 8192; m += nthr) {
        double xg = (double)(m - 4096) * (1.0 / 128.0);
        double th = alph * xg * xg;
        cA[m] = make_float2((float)cos(th), (float)sin(th));
    }
    const double gs = 1.0 / 8192.0;   // fold IFFT8192 norm into kernel spectra
    for (int q = gid; q < 8192; q += nthr) {
        double de = (q < 4096) ? (double)(2 * q) : (double)(2 * q - 16384);
        double u  = de * (1.0 / 128.0);
        double te = beta * u * u;
        gein[q] = make_float2((float)(cos(te) * gs), (float)(sin(te) * gs));
        double dl = (q < 4096) ? (double)(2 * q - 1) : (double)(2 * q - 16385);
        double v  = dl * (1.0 / 128.0);
        double to = beta * v * v;
        goin[q] = make_float2((float)(cos(to) * gs), (float)(sin(to) * gs));
    }
    // twist table (scrambled order): Gt[p] = s * exp(+i*pi*j/4096) / 4096, j = drev6(p)
    for (int p = gid; p < 4096; p += nthr) {
        const int j = drev6(p);
        double th = M_PI * (double)j / 4096.0;
        double ss = (j < 2048) ? (1.0 / 4096.0) : (-1.0 / 4096.0);
        Gt[p] = make_float2((float)(cos(th) * ss), (float)(sin(th) * ss));
    }
    if (gid == 0) {
        double sgn = (sp >= 0.0) ? 1.0 : -1.0;
        double ang = -(M_PI * sgn * 0.25 - phi * 0.5);
        double amp = 1.0 / sqrt(fabs(sp));
        sc[0] = make_float2((float)(cos(ang) * amp / 128.0),
                            (float)(sin(ang) * amp / 128.0));
    }
}

// blocks [0,ROWS): one row each. blocks ROWS,ROWS+1: FFT the conv kernels
// (GE/GO) and release a device-scope flag. 130 blocks <= 256 CUs -> all
// co-resident, so the row blocks' spin cannot deadlock.
__global__ __launch_bounds__(1024) void main_k(const float* __restrict__ x,
                                               char* __restrict__ ws,
                                               float* __restrict__ out,
                                               int write_complex) {
    __shared__ float re[8192];
    __shared__ float im[8192];
    const float2* tw = (const float2*)(ws + TW_OFF);
    const int t = threadIdx.x;
    unsigned* flags = (unsigned*)(ws + FLAG_OFF);

    if (blockIdx.x >= ROWS) {
        // ---- Ghat producer path ----
        const int kb = (int)blockIdx.x - ROWS;
        const float2* src = (const float2*)(ws + (kb == 0 ? GEIN_OFF : GOIN_OFF));
        float2*       dst = (float2*)      (ws + (kb == 0 ? GE_OFF   : GO_OFF));
#pragma unroll
        for (int j = 0; j < 8; ++j) {
            const int i = t + 1024 * j;
            const float2 v = src[i];
            re[swz(i)] = v.x; im[swz(i)] = v.y;
        }
        r2_8192<0>(re, im, tw, t);
        r4_stage<0, 12, 2>(re, im, tw, t);
        r4_stage<0, 10, 2>(re, im, tw, t);
        r4_stage<0,  8, 2>(re, im, tw, t);
        r4_stage<0,  6, 2>(re, im, tw, t);
        r4_stage<0,  4, 2>(re, im, tw, t);
        r4_stage<0,  2, 2>(re, im, tw, t);
        __syncthreads();
#pragma unroll
        for (int j = 0; j < 8; ++j) {
            const int i = t + 1024 * j;
            dst[i] = make_float2(re[swz(i)], im[swz(i)]);
        }
        __syncthreads();
        __threadfence();                       // device-scope: publish dst
        if (t == 0) atomicExch(&flags[kb], MAGIC);
        return;
    }

    // ---- row path ----
    const float2* cA = (const float2*)(ws + CA_OFF);
    const float2* GE = (const float2*)(ws + GE_OFF);
    const float2* GO = (const float2*)(ws + GO_OFF);
    const float2* Gt = (const float2*)(ws + GT_OFF);
    const float2  sc = *(const float2*)(ws + SC_OFF);
    const int row = blockIdx.x;

    // (1) load x (keep register copy: biz even samples ARE x)
    float xr[4];
#pragma unroll
    for (int c = 0; c < 4; ++c) {
        const int i = t + 1024 * c;
        xr[c] = x[row * NN + i];
        re[swz(i)] = xr[c]; im[swz(i)] = 0.f;
    }

    // (2) FFT4096(x) -> scrambled spectrum
    r4_stage<0, 12, 1>(re, im, tw, t);
    r4_stage<0, 10, 1>(re, im, tw, t);
    r4_stage<0,  8, 1>(re, im, tw, t);
    r4_stage<0,  6, 1>(re, im, tw, t);
    r4_stage<0,  4, 1>(re, im, tw, t);
    r4_stage<0,  2, 1>(re, im, tw, t);

    // (3) IFFT4096 with twist*Gt fused into first stage (q=0 -> unit twiddles)
    __syncthreads();
    {
        const int base = t << 2;
        float vr[4], vi[4];
#pragma unroll
        for (int c = 0; c < 4; ++c) {
            const int idx = swz(base + c);
            const float2 g = Gt[base + c];
            const float wr = re[idx], wi_ = im[idx];
            vr[c] = wr * g.x - wi_ * g.y;
            vi[c] = wr * g.y + wi_ * g.x;
        }
        const float s0r = vr[0] + vr[2], s0i = vi[0] + vi[2];
        const float s1r = vr[0] - vr[2], s1i = vi[0] - vi[2];
        const float s2r = vr[1] + vr[3], s2i = vi[1] + vi[3];
        const float s3r = vr[1] - vr[3], s3i = vi[1] - vi[3];
        re[swz(base)]     = s0r + s2r; im[swz(base)]     = s0i + s2i;
        re[swz(base + 1)] = s1r - s3i; im[swz(base + 1)] = s1i + s3r;
        re[swz(base + 2)] = s0r - s2r; im[swz(base + 2)] = s0i - s2i;
        re[swz(base + 3)] = s1r + s3i; im[swz(base + 3)] = s1i - s3r;
    }
    r4_stage<1,  4, 1>(re, im, tw, t);
    r4_stage<1,  6, 1>(re, im, tw, t);
    r4_stage<1,  8, 1>(re, im, tw, t);
    r4_stage<1, 10, 1>(re, im, tw, t);

    // (4) last IFFT4096 stage (LS=12) -> bo held in registers (real parts),
    //     positions t+1024c. No LDS write.
    float bo[4];
    __syncthreads();
    {
        const int q = t;
        const float ar = re[swz(t)],        ai = im[swz(t)];
        const float br = re[swz(t + 1024)], bi = im[swz(t + 1024)];
        const float cr = re[swz(t + 2048)], ci = im[swz(t + 2048)];
        const float dr = re[swz(t + 3072)], di = im[swz(t + 3072)];
        const float2 w1 = tw[q << 1];
        const float2 w2 = tw[(2 * q) << 1];
        const float2 w3 = tw[(3 * q) << 1];
        const float b1r = br * w1.x + bi * w1.y, b1i = bi * w1.x - br * w1.y;  // conj tw
        const float b2r = cr * w2.x + ci * w2.y, b2i = ci * w2.x - cr * w2.y;
        const float b3r = dr * w3.x + di * w3.y, b3i = di * w3.x - dr * w3.y;
        const float s0r = ar + b2r;
        const float s1r = ar - b2r;
        const float s2r = b1r + b3r;
        const float s3i = b1i - b3i;
        bo[0] = s0r + s2r;
        bo[1] = s1r - s3i;
        bo[2] = s0r - s2r;
        bo[3] = s1r + s3i;
    }
    __syncthreads();   // everyone done reading 4096 region before overwrite

    // (5) w_even = x*cA[2q]; zero-pad r2 stage fused into the write:
    //     buf[q] = w, buf[q+4096] = w*tw[q]
#pragma unroll
    for (int c = 0; c < 4; ++c) {
        const int q = t + 1024 * c;
        const float2 ce = cA[2 * q];
        const float wr = xr[c] * ce.x, wi_ = xr[c] * ce.y;
        const float2 w = tw[q];
        re[swz(q)] = wr;          im[swz(q)] = wi_;
        re[swz(q + 4096)] = wr * w.x - wi_ * w.y;
        im[swz(q + 4096)] = wr * w.y + wi_ * w.x;
    }
    r4_stage<0, 12, 2>(re, im, tw, t);
    r4_stage<0, 10, 2>(re, im, tw, t);
    r4_stage<0,  8, 2>(re, im, tw, t);
    r4_stage<0,  6, 2>(re, im, tw, t);
    r4_stage<0,  4, 2>(re, im, tw, t);
    r4_stage<0,  2, 2>(re, im, tw, t);

    // wait for Ghat tables (producers finish long before we get here)
    if (t == 0) {
        while (atomicCAS(&flags[0], 0u, 0u) != MAGIC) {}
        while (atomicCAS(&flags[1], 0u, 0u) != MAGIC) {}
    }
    __syncthreads();
    __threadfence();   // acquire

    // (6) ye = What_e * GE stashed in regs; then write w_odd into the SAME
    //     slots this thread just read (no barrier needed between).
    float yer[8], yei[8];
#pragma unroll
    for (int j = 0; j < 8; ++j) {
        const int p = t + 1024 * j;
        const int idx = swz(p);
        const float2 g = GE[p];
        const float wr = re[idx], wi_ = im[idx];
        yer[j] = wr * g.x - wi_ * g.y;
        yei[j] = wr * g.y + wi_ * g.x;
    }
#pragma unroll
    for (int c = 0; c < 4; ++c) {
        const int q = t + 1024 * c;
        const float2 co = cA[2 * q + 1];
        const float wr = bo[c] * co.x, wi_ = bo[c] * co.y;
        const float2 w = tw[q];
        re[swz(q)] = wr;          im[swz(q)] = wi_;
        re[swz(q + 4096)] = wr * w.x - wi_ * w.y;
        im[swz(q + 4096)] = wr * w.y + wi_ * w.x;
    }
    r4_stage<0, 12, 2>(re, im, tw, t);
    r4_stage<0, 10, 2>(re, im, tw, t);
    r4_stage<0,  8, 2>(re, im, tw, t);
    r4_stage<0,  6, 2>(re, im, tw, t);
    r4_stage<0,  4, 2>(re, im, tw, t);
    r4_stage<0,  2, 2>(re, im, tw, t);

    // (7) Y = ye + What_o * GO (read-modify-write own slots)
    __syncthreads();
#pragma unroll
    for (int j = 0; j < 8; ++j) {
        const int p = t + 1024 * j;
        const int idx = swz(p);
        const float2 g = GO[p];
        const float wr = re[idx], wi_ = im[idx];
        re[idx] = yer[j] + wr * g.x - wi_ * g.y;
        im[idx] = yei[j] + wr * g.y + wi_ * g.x;
    }

    // (8) IFFT8192, final r2 stage fused into output (only o<4096 needed)
    r4_stage<1,  2, 2>(re, im, tw, t);
    r4_stage<1,  4, 2>(re, im, tw, t);
    r4_stage<1,  6, 2>(re, im, tw, t);
    r4_stage<1,  8, 2>(re, im, tw, t);
    r4_stage<1, 10, 2>(re, im, tw, t);
    r4_stage<1, 12, 2>(re, im, tw, t);

    __syncthreads();
#pragma unroll
    for (int c = 0; c < 4; ++c) {
        const int o = t + 1024 * c;
        const float ur = re[swz(o)],        ui = im[swz(o)];
        const float vr = re[swz(o + 4096)], vi = im[swz(o + 4096)];
        const float2 w = tw[o];
        const float br = vr * w.x + vi * w.y;   // v * conj(tw[o])
        const float bi = vi * w.x - vr * w.y;
        const float yr = ur + br, yi = ui + bi;
        const float2 cc = cA[2 * o];
        const float tr = yr * cc.x - yi * cc.y;
        const float ti = yr * cc.y + yi * cc.x;
        float rr = tr * sc.x - ti * sc.y;
        float ri = tr * sc.y + ti * sc.x;
        if (o == 0) { rr *= 2.f; ri *= 2.f; }
        const int gi = row * NN + o;
        if (write_complex) { out[2 * gi] = rr; out[2 * gi + 1] = ri; }
        else               { out[gi] = rr; }
    }
}

extern "C" void kernel_launch(void* const* d_in, const int* in_sizes, int n_in,
                              void* d_out, int out_size, void* d_ws, size_t ws_size,
                              hipStream_t stream) {
    const float* x     = (const float*)d_in[0];
    const float* order = (const float*)d_in[1];
    float* out = (float*)d_out;
    char*  ws  = (char*)d_ws;
    const int write_complex = (out_size >= 2 * ROWS * NN) ? 1 : 0;

    hipLaunchKernelGGL(build_tables_k, dim3(64), dim3(256), 0, stream, order, ws);
    hipLaunchKernelGGL(main_k, dim3(ROWS + 2), dim3(1024), 0, stream,
                       x, ws, out, write_complex);
}

// Round 12
// 125.293 us; speedup vs baseline: 1.3578x; 1.3578x over previous
//
#include <hip/hip_runtime.h>
#include <math.h>

#ifndef M_PI
#define M_PI 3.14159265358979323846
#endif

#define ROWS 128
#define NN   4096

// ws byte offsets
#define TW_OFF   0        // float2[8192]  tw[k] = exp(-2*pi*i*k/8192)
#define CA_OFF   65536    // float2[8192]  cA[m] = chirp[4096+m]
#define GEIN_OFF 131072   // float2[8192]  Ec_even/8192 (time domain, natural)
#define GOIN_OFF 196608   // float2[8192]  Ec_odd /8192 (time domain, natural)
#define GE_OFF   262144   // float2[8192]  DIF8192(gein)  (scrambled order)
#define GO_OFF   327680   // float2[8192]  DIF8192(goin)  (scrambled order)
#define SC_OFF   393216   // float2        Aphi/128
#define GT_OFF   458752   // float2[4096]  twist table g[drev6(p)]/4096 (scrambled)

// LDS bank-conflict swizzle (bijective within [0,8192) and [0,4096))
__device__ __forceinline__ int swz(int i) { return i ^ ((i >> 5) & 31); }

// base-4 digit reversal of a 12-bit value (6 digits)
__device__ __forceinline__ int drev6(int v) {
    unsigned r = __brev((unsigned)v) >> 20;
    return (int)(((r & 0x555u) << 1) | ((r & 0xAAAu) >> 1));
}

// ---- radix-2 stage, span 8192 (g_fft path only) ----
template<int INV>
__device__ __forceinline__ void r2_8192(float* re, float* im,
                                        const float2* __restrict__ tw, int tid) {
    __syncthreads();
#pragma unroll
    for (int it = 0; it < 4; ++it) {
        const int n = tid + it * 1024;
        const int i0 = swz(n), i1 = swz(n + 4096);
        const float ur = re[i0], ui = im[i0];
        const float vr = re[i1], vi = im[i1];
        const float2 w = tw[n];
        const float wi = INV ? -w.y : w.y;
        if (!INV) {
            const float dr = ur - vr, di = ui - vi;
            re[i0] = ur + vr;            im[i0] = ui + vi;
            re[i1] = dr * w.x - di * wi; im[i1] = dr * wi + di * w.x;
        } else {
            const float br = vr * w.x - vi * wi, bi = vr * wi + vi * w.x;
            re[i0] = ur + br; im[i0] = ui + bi;
            re[i1] = ur - br; im[i1] = ui - bi;
        }
    }
}

// ---- radix-4 stage, span 2^LS. NITER=1: 4096-pt array, NITER=2: 8192-pt ----
// tw is 8192-based; twiddle shift 13-LS valid for both sizes.
template<int INV, int LS, int NITER>
__device__ __forceinline__ void r4_stage(float* re, float* im,
                                         const float2* __restrict__ tw, int tid) {
    __syncthreads();
    const int Q = 1 << (LS - 2);
    const int TS = 13 - LS;
#pragma unroll
    for (int it = 0; it < NITER; ++it) {
        const int gi = tid + it * 1024;
        const int q  = gi & (Q - 1);
        const int base = ((gi >> (LS - 2)) << LS) | q;
        const int i0 = swz(base), i1 = swz(base + Q), i2 = swz(base + 2 * Q), i3 = swz(base + 3 * Q);
        float ar = re[i0], ai = im[i0];
        float br = re[i1], bi = im[i1];
        float cr = re[i2], ci = im[i2];
        float dr = re[i3], di = im[i3];
        const float2 w1 = tw[q << TS];
        const float2 w2 = tw[(2 * q) << TS];
        const float2 w3 = tw[(3 * q) << TS];
        const float w1i = INV ? -w1.y : w1.y;
        const float w2i = INV ? -w2.y : w2.y;
        const float w3i = INV ? -w3.y : w3.y;
        if (!INV) {
            const float t0r = ar + cr, t0i = ai + ci;
            const float t1r = ar - cr, t1i = ai - ci;
            const float t2r = br + dr, t2i = bi + di;
            const float t3r = br - dr, t3i = bi - di;
            re[i0] = t0r + t2r; im[i0] = t0i + t2i;
            const float y1r = t1r + t3i, y1i = t1i - t3r;
            re[i1] = y1r * w1.x - y1i * w1i; im[i1] = y1r * w1i + y1i * w1.x;
            const float y2r = t0r - t2r, y2i = t0i - t2i;
            re[i2] = y2r * w2.x - y2i * w2i; im[i2] = y2r * w2i + y2i * w2.x;
            const float y3r = t1r - t3i, y3i = t1i + t3r;
            re[i3] = y3r * w3.x - y3i * w3i; im[i3] = y3r * w3i + y3i * w3.x;
        } else {
            const float b1r = br * w1.x - bi * w1i, b1i = br * w1i + bi * w1.x;
            const float b2r = cr * w2.x - ci * w2i, b2i = cr * w2i + ci * w2.x;
            const float b3r = dr * w3.x - di * w3i, b3i = dr * w3i + di * w3.x;
            const float s0r = ar + b2r, s0i = ai + b2i;
            const float s1r = ar - b2r, s1i = ai - b2i;
            const float s2r = b1r + b3r, s2i = b1i + b3i;
            const float s3r = b1r - b3r, s3i = b1i - b3i;
            re[i0] = s0r + s2r; im[i0] = s0i + s2i;
            re[i1] = s1r - s3i; im[i1] = s1i + s3r;
            re[i2] = s0r - s2r; im[i2] = s0i - s2i;
            re[i3] = s1r + s3i; im[i3] = s1i - s3r;
        }
    }
}

__global__ __launch_bounds__(256) void build_tables_k(const float* __restrict__ order,
                                                      char* __restrict__ ws) {
    const int gid  = blockIdx.x * 256 + threadIdx.x;
    const int nthr = gridDim.x * 256;
    const double a    = (double)order[0];
    const double phi  = a * (M_PI * 0.5);
    const double sp   = sin(phi);
    const double alph = -M_PI * tan(phi * 0.5);
    const double beta = M_PI / sp;
    float2* tw   = (float2*)(ws + TW_OFF);
    float2* cA   = (float2*)(ws + CA_OFF);
    float2* gein = (float2*)(ws + GEIN_OFF);
    float2* goin = (float2*)(ws + GOIN_OFF);
    float2* sc   = (float2*)(ws + SC_OFF);
    float2* Gt   = (float2*)(ws + GT_OFF);
    for (int k = gid; k < 8192; k += nthr) {
        double th = -2.0 * M_PI * (double)k / 8192.0;
        tw[k] = make_float2((float)cos(th), (float)sin(th));
    }
    for (int m = gid; m < 8192; m += nthr) {
        double xg = (double)(m - 4096) * (1.0 / 128.0);
        double th = alph * xg * xg;
        cA[m] = make_float2((float)cos(th), (float)sin(th));
    }
    const double gs = 1.0 / 8192.0;   // fold IFFT8192 norm into kernel spectra
    for (int q = gid; q < 8192; q += nthr) {
        double de = (q < 4096) ? (double)(2 * q) : (double)(2 * q - 16384);
        double u  = de * (1.0 / 128.0);
        double te = beta * u * u;
        gein[q] = make_float2((float)(cos(te) * gs), (float)(sin(te) * gs));
        double dl = (q < 4096) ? (double)(2 * q - 1) : (double)(2 * q - 16385);
        double v  = dl * (1.0 / 128.0);
        double to = beta * v * v;
        goin[q] = make_float2((float)(cos(to) * gs), (float)(sin(to) * gs));
    }
    // twist table (scrambled order): Gt[p] = s * exp(+i*pi*j/4096) / 4096, j = drev6(p)
    for (int p = gid; p < 4096; p += nthr) {
        const int j = drev6(p);
        double th = M_PI * (double)j / 4096.0;
        double ss = (j < 2048) ? (1.0 / 4096.0) : (-1.0 / 4096.0);
        Gt[p] = make_float2((float)(cos(th) * ss), (float)(sin(th) * ss));
    }
    if (gid == 0) {
        double sgn = (sp >= 0.0) ? 1.0 : -1.0;
        double ang = -(M_PI * sgn * 0.25 - phi * 0.5);
        double amp = 1.0 / sqrt(fabs(sp));
        sc[0] = make_float2((float)(cos(ang) * amp / 128.0),
                            (float)(sin(ang) * amp / 128.0));
    }
}

// FFT the two conv kernels (scrambled DIF order): block0 -> GE, block1 -> GO
__global__ __launch_bounds__(1024) void g_fft_k(char* __restrict__ ws) {
    __shared__ float re[8192];
    __shared__ float im[8192];
    const float2* tw  = (const float2*)(ws + TW_OFF);
    const float2* src = (const float2*)(ws + (blockIdx.x == 0 ? GEIN_OFF : GOIN_OFF));
    float2*       dst = (float2*)      (ws + (blockIdx.x == 0 ? GE_OFF   : GO_OFF));
    const int t = threadIdx.x;
#pragma unroll
    for (int j = 0; j < 8; ++j) {
        const int i = t + 1024 * j;
        const float2 v = src[i];
        re[swz(i)] = v.x; im[swz(i)] = v.y;
    }
    r2_8192<0>(re, im, tw, t);
    r4_stage<0, 12, 2>(re, im, tw, t);
    r4_stage<0, 10, 2>(re, im, tw, t);
    r4_stage<0,  8, 2>(re, im, tw, t);
    r4_stage<0,  6, 2>(re, im, tw, t);
    r4_stage<0,  4, 2>(re, im, tw, t);
    r4_stage<0,  2, 2>(re, im, tw, t);
    __syncthreads();
#pragma unroll
    for (int j = 0; j < 8; ++j) {
        const int i = t + 1024 * j;
        dst[i] = make_float2(re[swz(i)], im[swz(i)]);
    }
}

__global__ __launch_bounds__(1024) void row_k(const float* __restrict__ x,
                                              const char* __restrict__ ws,
                                              float* __restrict__ out,
                                              int write_complex) {
    __shared__ float re[8192];
    __shared__ float im[8192];
    const float2* tw = (const float2*)(ws + TW_OFF);
    const float2* cA = (const float2*)(ws + CA_OFF);
    const float2* GE = (const float2*)(ws + GE_OFF);
    const float2* GO = (const float2*)(ws + GO_OFF);
    const float2* Gt = (const float2*)(ws + GT_OFF);
    const float2  sc = *(const float2*)(ws + SC_OFF);
    const int row = blockIdx.x;
    const int t   = threadIdx.x;

    // (1) load x (keep register copy: biz even samples ARE x)
    float xr[4];
#pragma unroll
    for (int c = 0; c < 4; ++c) {
        const int i = t + 1024 * c;
        xr[c] = x[row * NN + i];
        re[swz(i)] = xr[c]; im[swz(i)] = 0.f;
    }

    // (2) FFT4096(x) -> scrambled spectrum
    r4_stage<0, 12, 1>(re, im, tw, t);
    r4_stage<0, 10, 1>(re, im, tw, t);
    r4_stage<0,  8, 1>(re, im, tw, t);
    r4_stage<0,  6, 1>(re, im, tw, t);
    r4_stage<0,  4, 1>(re, im, tw, t);
    r4_stage<0,  2, 1>(re, im, tw, t);

    // (3) IFFT4096 with twist*Gt fused into first stage (q=0 -> unit twiddles)
    __syncthreads();
    {
        const int base = t << 2;
        float vr[4], vi[4];
#pragma unroll
        for (int c = 0; c < 4; ++c) {
            const int idx = swz(base + c);
            const float2 g = Gt[base + c];
            const float wr = re[idx], wi_ = im[idx];
            vr[c] = wr * g.x - wi_ * g.y;
            vi[c] = wr * g.y + wi_ * g.x;
        }
        const float s0r = vr[0] + vr[2], s0i = vi[0] + vi[2];
        const float s1r = vr[0] - vr[2], s1i = vi[0] - vi[2];
        const float s2r = vr[1] + vr[3], s2i = vi[1] + vi[3];
        const float s3r = vr[1] - vr[3], s3i = vi[1] - vi[3];
        re[swz(base)]     = s0r + s2r; im[swz(base)]     = s0i + s2i;
        re[swz(base + 1)] = s1r - s3i; im[swz(base + 1)] = s1i + s3r;
        re[swz(base + 2)] = s0r - s2r; im[swz(base + 2)] = s0i - s2i;
        re[swz(base + 3)] = s1r + s3i; im[swz(base + 3)] = s1i - s3r;
    }
    r4_stage<1,  4, 1>(re, im, tw, t);
    r4_stage<1,  6, 1>(re, im, tw, t);
    r4_stage<1,  8, 1>(re, im, tw, t);
    r4_stage<1, 10, 1>(re, im, tw, t);

    // (4) last IFFT4096 stage (LS=12) -> bo held in registers (real parts)
    float bo[4];
    __syncthreads();
    {
        const int q = t;
        const float ar = re[swz(t)];
        const float br = re[swz(t + 1024)], bi = im[swz(t + 1024)];
        const float cr = re[swz(t + 2048)], ci = im[swz(t + 2048)];
        const float dr = re[swz(t + 3072)], di = im[swz(t + 3072)];
        const float2 w1 = tw[q << 1];
        const float2 w2 = tw[(2 * q) << 1];
        const float2 w3 = tw[(3 * q) << 1];
        const float b1r = br * w1.x + bi * w1.y, b1i = bi * w1.x - br * w1.y;  // conj tw
        const float b2r = cr * w2.x + ci * w2.y;
        const float b3r = dr * w3.x + di * w3.y, b3i = di * w3.x - dr * w3.y;
        const float s0r = ar + b2r;
        const float s1r = ar - b2r;
        const float s2r = b1r + b3r;
        const float s3i = b1i - b3i;
        bo[0] = s0r + s2r;
        bo[1] = s1r - s3i;
        bo[2] = s0r - s2r;
        bo[3] = s1r + s3i;
    }
    __syncthreads();   // everyone done reading before overwrite

    // (5) w_even = x*cA[2q]; zero-pad r2 stage fused into the write
#pragma unroll
    for (int c = 0; c < 4; ++c) {
        const int q = t + 1024 * c;
        const float2 ce = cA[2 * q];
        const float wr = xr[c] * ce.x, wi_ = xr[c] * ce.y;
        const float2 w = tw[q];
        re[swz(q)] = wr;          im[swz(q)] = wi_;
        re[swz(q + 4096)] = wr * w.x - wi_ * w.y;
        im[swz(q + 4096)] = wr * w.y + wi_ * w.x;
    }
    r4_stage<0, 12, 2>(re, im, tw, t);
    r4_stage<0, 10, 2>(re, im, tw, t);
    r4_stage<0,  8, 2>(re, im, tw, t);
    r4_stage<0,  6, 2>(re, im, tw, t);
    r4_stage<0,  4, 2>(re, im, tw, t);
    r4_stage<0,  2, 2>(re, im, tw, t);

    // (6) ye = What_e * GE stashed in regs; then write w_odd into the SAME
    //     slots this thread just read (disjoint per thread -> no barrier).
    __syncthreads();
    float yer[8], yei[8];
#pragma unroll
    for (int j = 0; j < 8; ++j) {
        const int p = t + 1024 * j;
        const int idx = swz(p);
        const float2 g = GE[p];
        const float wr = re[idx], wi_ = im[idx];
        yer[j] = wr * g.x - wi_ * g.y;
        yei[j] = wr * g.y + wi_ * g.x;
    }
#pragma unroll
    for (int c = 0; c < 4; ++c) {
        const int q = t + 1024 * c;
        const float2 co = cA[2 * q + 1];
        const float wr = bo[c] * co.x, wi_ = bo[c] * co.y;
        const float2 w = tw[q];
        re[swz(q)] = wr;          im[swz(q)] = wi_;
        re[swz(q + 4096)] = wr * w.x - wi_ * w.y;
        im[swz(q + 4096)] = wr * w.y + wi_ * w.x;
    }
    r4_stage<0, 12, 2>(re, im, tw, t);
    r4_stage<0, 10, 2>(re, im, tw, t);
    r4_stage<0,  8, 2>(re, im, tw, t);
    r4_stage<0,  6, 2>(re, im, tw, t);
    r4_stage<0,  4, 2>(re, im, tw, t);
    r4_stage<0,  2, 2>(re, im, tw, t);

    // (7) Y = ye + What_o * GO (read-modify-write own slots)
    __syncthreads();
#pragma unroll
    for (int j = 0; j < 8; ++j) {
        const int p = t + 1024 * j;
        const int idx = swz(p);
        const float2 g = GO[p];
        const float wr = re[idx], wi_ = im[idx];
        re[idx] = yer[j] + wr * g.x - wi_ * g.y;
        im[idx] = yei[j] + wr * g.y + wi_ * g.x;
    }

    // (8) IFFT8192, final r2 stage fused into output (only o<4096 needed)
    r4_stage<1,  2, 2>(re, im, tw, t);
    r4_stage<1,  4, 2>(re, im, tw, t);
    r4_stage<1,  6, 2>(re, im, tw, t);
    r4_stage<1,  8, 2>(re, im, tw, t);
    r4_stage<1, 10, 2>(re, im, tw, t);
    r4_stage<1, 12, 2>(re, im, tw, t);

    __syncthreads();
#pragma unroll
    for (int c = 0; c < 4; ++c) {
        const int o = t + 1024 * c;
        const float ur = re[swz(o)],        ui = im[swz(o)];
        const float vr = re[swz(o + 4096)], vi = im[swz(o + 4096)];
        const float2 w = tw[o];
        const float br = vr * w.x + vi * w.y;   // v * conj(tw[o])
        const float bi = vi * w.x - vr * w.y;
        const float yr = ur + br, yi = ui + bi;
        const float2 cc = cA[2 * o];
        const float tr = yr * cc.x - yi * cc.y;
        const float ti = yr * cc.y + yi * cc.x;
        float rr = tr * sc.x - ti * sc.y;
        float ri = tr * sc.y + ti * sc.x;
        if (o == 0) { rr *= 2.f; ri *= 2.f; }
        const int gi = row * NN + o;
        if (write_complex) { out[2 * gi] = rr; out[2 * gi + 1] = ri; }
        else               { out[gi] = rr; }
    }
}

extern "C" void kernel_launch(void* const* d_in, const int* in_sizes, int n_in,
                              void* d_out, int out_size, void* d_ws, size_t ws_size,
                              hipStream_t stream) {
    const float* x     = (const float*)d_in[0];
    const float* order = (const float*)d_in[1];
    float* out = (float*)d_out;
    char*  ws  = (char*)d_ws;
    const int write_complex = (out_size >= 2 * ROWS * NN) ? 1 : 0;

    hipLaunchKernelGGL(build_tables_k, dim3(64), dim3(256), 0, stream, order, ws);
    hipLaunchKernelGGL(g_fft_k, dim3(2), dim3(1024), 0, stream, ws);
    hipLaunchKernelGGL(row_k, dim3(ROWS), dim3(1024), 0, stream, x, ws, out, write_complex);
}